// Round 7
// baseline (363.579 us; speedup 1.0000x reference)
//
#include <hip/hip_runtime.h>
#include <math.h>

#define N_NODES_C 100000
#define N_EDGES_C 1600000
#define IN_DIM_C 64
#define HID_C 128
#define N_ASSETS_C 50
#define N_GRAPHS_C 64

#define BKT_SHIFT 9
#define BKT_NODES 512
#define NB_BKT ((N_NODES_C + BKT_NODES - 1) / BKT_NODES)   // 196
#define EPB_A 8192
#define NBLK_A ((N_EDGES_C + EPB_A - 1) / EPB_A)            // 196

typedef __attribute__((ext_vector_type(8))) short bf16x8;
typedef __attribute__((ext_vector_type(4))) float f32x4;

__device__ __forceinline__ unsigned short f2bf(float f) {
    unsigned u = __float_as_uint(f);
    return (unsigned short)((u + 0x7FFFu + ((u >> 16) & 1u)) >> 16);
}
__device__ __forceinline__ float bf2f(unsigned short b) {
    return __uint_as_float((unsigned)b << 16);
}
__device__ __forceinline__ void acc_bf8(float* acc, uint4 v) {
    acc[0] += __uint_as_float(v.x << 16);
    acc[1] += __uint_as_float(v.x & 0xFFFF0000u);
    acc[2] += __uint_as_float(v.y << 16);
    acc[3] += __uint_as_float(v.y & 0xFFFF0000u);
    acc[4] += __uint_as_float(v.z << 16);
    acc[5] += __uint_as_float(v.z & 0xFFFF0000u);
    acc[6] += __uint_as_float(v.w << 16);
    acc[7] += __uint_as_float(v.w & 0xFFFF0000u);
}
// 4 fp8 (one dword) -> acc[0..3]
__device__ __forceinline__ void acc_fp8x4(float* acc, unsigned v) {
    auto p0 = __builtin_amdgcn_cvt_pk_f32_fp8((int)v, false);
    auto p1 = __builtin_amdgcn_cvt_pk_f32_fp8((int)v, true);
    acc[0] += p0[0]; acc[1] += p0[1]; acc[2] += p1[0]; acc[3] += p1[1];
}
__device__ __forceinline__ void acc_fp8x16(float* acc, uint4 v) {
    acc_fp8x4(acc + 0,  v.x);
    acc_fp8x4(acc + 4,  v.y);
    acc_fp8x4(acc + 8,  v.z);
    acc_fp8x4(acc + 12, v.w);
}

// ---------------------------------------------------------------------------
// fp32 -> bf16 cast (vectorized), n4 = count/4
// ---------------------------------------------------------------------------
__global__ __launch_bounds__(256) void cast_bf16_kernel(
    const float* __restrict__ src, unsigned short* __restrict__ dst, int n4)
{
    int i = blockIdx.x * 256 + threadIdx.x;
    if (i < n4) {
        float4 v = ((const float4*)src)[i];
        ushort4 o;
        o.x = f2bf(v.x); o.y = f2bf(v.y); o.z = f2bf(v.z); o.w = f2bf(v.w);
        ((ushort4*)dst)[i] = o;
    }
}

// ---------------------------------------------------------------------------
// bf16 -> fp8 e4m3 cast, 8 elems/thread. n8 = count/8
// ---------------------------------------------------------------------------
__global__ __launch_bounds__(256) void cast_fp8_kernel(
    const unsigned short* __restrict__ src, unsigned char* __restrict__ dst, int n8)
{
    int i = blockIdx.x * 256 + threadIdx.x;
    if (i < n8) {
        uint4 v = ((const uint4*)src)[i];
        float f0 = __uint_as_float(v.x << 16), f1 = __uint_as_float(v.x & 0xFFFF0000u);
        float f2 = __uint_as_float(v.y << 16), f3 = __uint_as_float(v.y & 0xFFFF0000u);
        float f4 = __uint_as_float(v.z << 16), f5 = __uint_as_float(v.z & 0xFFFF0000u);
        float f6 = __uint_as_float(v.w << 16), f7 = __uint_as_float(v.w & 0xFFFF0000u);
        int lo = 0, hi = 0;
        lo = __builtin_amdgcn_cvt_pk_fp8_f32(f0, f1, lo, false);
        lo = __builtin_amdgcn_cvt_pk_fp8_f32(f2, f3, lo, true);
        hi = __builtin_amdgcn_cvt_pk_fp8_f32(f4, f5, hi, false);
        hi = __builtin_amdgcn_cvt_pk_fp8_f32(f6, f7, hi, true);
        uint2 o; o.x = (unsigned)lo; o.y = (unsigned)hi;
        ((uint2*)dst)[i] = o;
    }
}

// ---------------------------------------------------------------------------
// Pack fp32 weight [Kw x 128] into MFMA B-fragments, split hi/lo bf16.
// ---------------------------------------------------------------------------
__global__ __launch_bounds__(64) void pack_w_kernel(
    const float* __restrict__ W, unsigned short* __restrict__ dst)
{
    int kc = blockIdx.x >> 3;
    int ct = blockIdx.x & 7;
    int lane = threadIdx.x;
    int quad = lane >> 4;
    int l16 = lane & 15;
    unsigned short hi[8], lo[8];
#pragma unroll
    for (int j = 0; j < 8; ++j) {
        float w = W[(size_t)(kc * 32 + quad * 8 + j) * HID_C + ct * 16 + l16];
        unsigned short h = f2bf(w);
        float r = w - bf2f(h);
        hi[j] = h;
        lo[j] = f2bf(r);
    }
    size_t base = ((size_t)(kc * 8 + ct) * 2) * 512 + (size_t)lane * 8;
#pragma unroll
    for (int j = 0; j < 8; ++j) {
        dst[base + j] = hi[j];
        dst[base + 512 + j] = lo[j];
    }
}

// ---------------------------------------------------------------------------
// CSR build: bucketed counting sort.
// ---------------------------------------------------------------------------
__global__ __launch_bounds__(256) void bucket_hist_kernel(
    const int* __restrict__ ei, int* __restrict__ bcnt)
{
    __shared__ int cnt[NB_BKT];
    int t = threadIdx.x;
    for (int i = t; i < NB_BKT; i += 256) cnt[i] = 0;
    __syncthreads();
    int base = blockIdx.x * 2048;
#pragma unroll
    for (int i = 0; i < 8; ++i) {
        int e = base + i * 256 + t;
        if (e < N_EDGES_C) {
            int dst = ei[N_EDGES_C + e];
            atomicAdd(&cnt[dst >> BKT_SHIFT], 1);
        }
    }
    __syncthreads();
    for (int i = t; i < NB_BKT; i += 256)
        if (cnt[i]) atomicAdd(&bcnt[i], cnt[i]);
}

__global__ __launch_bounds__(256) void bucket_scan_kernel(
    const int* __restrict__ bcnt, int* __restrict__ bbase, int* __restrict__ gcur)
{
    __shared__ int s[256];
    int t = threadIdx.x;
    int v = (t < NB_BKT) ? bcnt[t] : 0;
    s[t] = v;
    __syncthreads();
    for (int o = 1; o < 256; o <<= 1) {
        int x = (t >= o) ? s[t - o] : 0;
        __syncthreads();
        s[t] += x;
        __syncthreads();
    }
    int excl = s[t] - v;
    if (t < NB_BKT) { bbase[t] = excl; gcur[t] = excl; }
    if (t == 255) bbase[NB_BKT] = s[255];
}

__global__ __launch_bounds__(256) void partition_kernel(
    const int* __restrict__ ei, int* __restrict__ gcur,
    unsigned* __restrict__ tmp)
{
    __shared__ unsigned stage[EPB_A];
    __shared__ unsigned stage2[EPB_A];
    __shared__ unsigned char sbkt[EPB_A];
    __shared__ unsigned char sbkt2[EPB_A];
    __shared__ int cnt[NB_BKT];
    __shared__ int base[NB_BKT];
    __shared__ int cur[NB_BKT];
    __shared__ int gb[NB_BKT];
    __shared__ int s[256];

    const int t = threadIdx.x;
    const int e0 = blockIdx.x * EPB_A;
    const int nE = min(EPB_A, N_EDGES_C - e0);

    for (int i = t; i < NB_BKT; i += 256) cnt[i] = 0;
    __syncthreads();

    for (int idx = t; idx < nE; idx += 256) {
        int e = e0 + idx;
        int src = ei[e];
        int dst = ei[N_EDGES_C + e];
        int b = dst >> BKT_SHIFT;
        stage[idx] = ((unsigned)(dst & (BKT_NODES - 1)) << 17) | (unsigned)src;
        sbkt[idx] = (unsigned char)b;
        atomicAdd(&cnt[b], 1);
    }
    __syncthreads();

    int v = (t < NB_BKT) ? cnt[t] : 0;
    s[t] = v;
    __syncthreads();
    for (int o = 1; o < 256; o <<= 1) {
        int x = (t >= o) ? s[t - o] : 0;
        __syncthreads();
        s[t] += x;
        __syncthreads();
    }
    if (t < NB_BKT) {
        int excl = s[t] - v;
        base[t] = excl;
        cur[t] = excl;
        gb[t] = atomicAdd(&gcur[t], v);
    }
    __syncthreads();

    for (int idx = t; idx < nE; idx += 256) {
        int b = sbkt[idx];
        int p = atomicAdd(&cur[b], 1);
        stage2[p] = stage[idx];
        sbkt2[p] = (unsigned char)b;
    }
    __syncthreads();

    for (int idx = t; idx < nE; idx += 256) {
        int b = sbkt2[idx];
        int dest = gb[b] + (idx - base[b]);
        tmp[dest] = stage2[idx];
    }
}

__global__ __launch_bounds__(256) void bucket_sort_kernel(
    const unsigned* __restrict__ tmp, const int* __restrict__ bbase,
    int* __restrict__ row_ptr, int* __restrict__ col)
{
    __shared__ int ldeg[BKT_NODES];
    __shared__ int lsum[256];
    const int t = threadIdx.x;
    const int b = blockIdx.x;
    const int beg = bbase[b];
    const int end = bbase[b + 1];

    ldeg[t] = 0; ldeg[t + 256] = 0;
    __syncthreads();

    for (int p = beg + t; p < end; p += 256)
        atomicAdd(&ldeg[tmp[p] >> 17], 1);
    __syncthreads();

    int a0 = ldeg[2 * t], a1 = ldeg[2 * t + 1];
    int pair = a0 + a1;
    lsum[t] = pair;
    __syncthreads();
    for (int o = 1; o < 256; o <<= 1) {
        int x = (t >= o) ? lsum[t - o] : 0;
        __syncthreads();
        lsum[t] += x;
        __syncthreads();
    }
    int ep = lsum[t] - pair;
    __syncthreads();
    ldeg[2 * t] = ep;
    ldeg[2 * t + 1] = ep + a0;

    int gn0 = b * BKT_NODES + 2 * t;
    if (gn0 < N_NODES_C)     row_ptr[gn0] = beg + ep;
    if (gn0 + 1 < N_NODES_C) row_ptr[gn0 + 1] = beg + ep + a0;
    if (b == NB_BKT - 1 && t == 0) row_ptr[N_NODES_C] = N_EDGES_C;
    __syncthreads();

    for (int p = beg + t; p < end; p += 256) {
        unsigned v = tmp[p];
        int pos = atomicAdd(&ldeg[v >> 17], 1);
        col[beg + pos] = (int)(v & 0x1FFFFu);
    }
}

// ---------------------------------------------------------------------------
// Layer-1 gather (bf16 x, 64-wide rows): 8-lane groups, dwordx4 loads.
// ---------------------------------------------------------------------------
__global__ __launch_bounds__(256) void gather_bf64_kernel(
    const unsigned short* __restrict__ feat, const int* __restrict__ row_ptr,
    const int* __restrict__ col, unsigned short* __restrict__ agg)
{
    int wave = threadIdx.x >> 6;
    int lane = threadIdx.x & 63;
    int g = lane >> 3;     // edge subgroup 0..7
    int c = lane & 7;      // 16B chunk within row (row = 8 x uint4)
    int n = blockIdx.x * 4 + wave;
    if (n >= N_NODES_C) return;
    int beg = row_ptr[n], end = row_ptr[n + 1];
    const uint4* f4 = (const uint4*)feat;

    float acc[8];
#pragma unroll
    for (int j = 0; j < 8; ++j) acc[j] = 0.f;

    int e = beg + g;
    for (; e + 8 < end; e += 16) {
        int s0 = col[e], s1 = col[e + 8];
        uint4 v0 = f4[(size_t)s0 * 8 + c];
        uint4 v1 = f4[(size_t)s1 * 8 + c];
        acc_bf8(acc, v0); acc_bf8(acc, v1);
    }
    if (e < end) {
        uint4 v = f4[(size_t)col[e] * 8 + c];
        acc_bf8(acc, v);
    }
#pragma unroll
    for (int j = 0; j < 8; ++j) {
        acc[j] += __shfl_xor(acc[j], 8, 64);
        acc[j] += __shfl_xor(acc[j], 16, 64);
        acc[j] += __shfl_xor(acc[j], 32, 64);
    }
    if (g == 0) {
        uint4 o;
        o.x = (unsigned)f2bf(acc[0]) | ((unsigned)f2bf(acc[1]) << 16);
        o.y = (unsigned)f2bf(acc[2]) | ((unsigned)f2bf(acc[3]) << 16);
        o.z = (unsigned)f2bf(acc[4]) | ((unsigned)f2bf(acc[5]) << 16);
        o.w = (unsigned)f2bf(acc[6]) | ((unsigned)f2bf(acc[7]) << 16);
        ((uint4*)agg)[(size_t)n * 8 + c] = o;
    }
}

// ---------------------------------------------------------------------------
// Layer-2 gather over fp8 rows (128 cols = 128 B = 8 x uint4):
// 8-lane groups -> 8 edges per VMEM instr, 16 in flight; fp32 acc; bf16 out.
// ---------------------------------------------------------------------------
__global__ __launch_bounds__(256) void gather_fp8_kernel(
    const unsigned char* __restrict__ feat, const int* __restrict__ row_ptr,
    const int* __restrict__ col, unsigned short* __restrict__ agg)
{
    int wave = threadIdx.x >> 6;
    int lane = threadIdx.x & 63;
    int g = lane >> 3;     // edge subgroup 0..7
    int c = lane & 7;      // 16B chunk (16 fp8 cols) within row
    int n = blockIdx.x * 4 + wave;
    if (n >= N_NODES_C) return;
    int beg = row_ptr[n], end = row_ptr[n + 1];
    const uint4* f4 = (const uint4*)feat;

    float acc[16];
#pragma unroll
    for (int j = 0; j < 16; ++j) acc[j] = 0.f;

    int e = beg + g;
    for (; e + 8 < end; e += 16) {
        int s0 = col[e], s1 = col[e + 8];
        uint4 v0 = f4[(size_t)s0 * 8 + c];
        uint4 v1 = f4[(size_t)s1 * 8 + c];
        acc_fp8x16(acc, v0); acc_fp8x16(acc, v1);
    }
    if (e < end) {
        uint4 v = f4[(size_t)col[e] * 8 + c];
        acc_fp8x16(acc, v);
    }
#pragma unroll
    for (int j = 0; j < 16; ++j) {
        acc[j] += __shfl_xor(acc[j], 8, 64);
        acc[j] += __shfl_xor(acc[j], 16, 64);
        acc[j] += __shfl_xor(acc[j], 32, 64);
    }
    if (g == 0) {
        // lane c holds cols c*16..c*16+15 -> 32 B bf16 = 2 uint4 stores
        uint4 o0, o1;
        o0.x = (unsigned)f2bf(acc[0])  | ((unsigned)f2bf(acc[1])  << 16);
        o0.y = (unsigned)f2bf(acc[2])  | ((unsigned)f2bf(acc[3])  << 16);
        o0.z = (unsigned)f2bf(acc[4])  | ((unsigned)f2bf(acc[5])  << 16);
        o0.w = (unsigned)f2bf(acc[6])  | ((unsigned)f2bf(acc[7])  << 16);
        o1.x = (unsigned)f2bf(acc[8])  | ((unsigned)f2bf(acc[9])  << 16);
        o1.y = (unsigned)f2bf(acc[10]) | ((unsigned)f2bf(acc[11]) << 16);
        o1.z = (unsigned)f2bf(acc[12]) | ((unsigned)f2bf(acc[13]) << 16);
        o1.w = (unsigned)f2bf(acc[14]) | ((unsigned)f2bf(acc[15]) << 16);
        ((uint4*)agg)[(size_t)n * 16 + c * 2]     = o0;
        ((uint4*)agg)[(size_t)n * 16 + c * 2 + 1] = o1;
    }
}

// ---------------------------------------------------------------------------
// MFMA conv phase: acc += [P rows] @ [WP hi] + [P rows] @ [WP lo]
// ---------------------------------------------------------------------------
template<int K>
__device__ __forceinline__ void conv_phase(
    const unsigned short* __restrict__ P, const unsigned short* __restrict__ WP,
    const int* rowIdx, int quad, int lane, int wv, f32x4 acc[4][2])
{
#pragma unroll
    for (int kc = 0; kc < K / 32; ++kc) {
        bf16x8 afr[4];
#pragma unroll
        for (int rt = 0; rt < 4; ++rt)
            afr[rt] = *(const bf16x8*)(P + (size_t)rowIdx[rt] * K + kc * 32 + quad * 8);
#pragma unroll
        for (int ci = 0; ci < 2; ++ci) {
            int ct = wv * 2 + ci;
            const unsigned short* bp = WP + ((size_t)(kc * 8 + ct) * 2) * 512 + (size_t)lane * 8;
            bf16x8 bhi = *(const bf16x8*)bp;
            bf16x8 blo = *(const bf16x8*)(bp + 512);
#pragma unroll
            for (int rt = 0; rt < 4; ++rt) {
                acc[rt][ci] = __builtin_amdgcn_mfma_f32_16x16x32_bf16(afr[rt], bhi, acc[rt][ci], 0, 0, 0);
                acc[rt][ci] = __builtin_amdgcn_mfma_f32_16x16x32_bf16(afr[rt], blo, acc[rt][ci], 0, 0, 0);
            }
        }
    }
}

// Layer-1 conv: bf16 out.
template<int KA, int KX>
__global__ __launch_bounds__(256) void conv_mfma_kernel(
    const unsigned short* __restrict__ A, const unsigned short* __restrict__ X,
    const unsigned short* __restrict__ WrP, const unsigned short* __restrict__ WoP,
    const float* __restrict__ bias, unsigned short* __restrict__ outp, int N)
{
    const int t = threadIdx.x;
    const int wv = t >> 6;
    const int lane = t & 63;
    const int quad = lane >> 4;
    const int l16 = lane & 15;
    const int n0 = blockIdx.x * 64;

    f32x4 acc[4][2];
#pragma unroll
    for (int rt = 0; rt < 4; ++rt)
#pragma unroll
        for (int ci = 0; ci < 2; ++ci)
            acc[rt][ci] = (f32x4){0.f, 0.f, 0.f, 0.f};

    int rowIdx[4];
#pragma unroll
    for (int rt = 0; rt < 4; ++rt) {
        int r = n0 + rt * 16 + l16;
        rowIdx[rt] = (r < N) ? r : (N - 1);
    }

    conv_phase<KA>(A, WrP, rowIdx, quad, lane, wv, acc);
    conv_phase<KX>(X, WoP, rowIdx, quad, lane, wv, acc);

#pragma unroll
    for (int ci = 0; ci < 2; ++ci) {
        int colg = wv * 32 + ci * 16 + l16;
        float bv = bias[colg];
#pragma unroll
        for (int rt = 0; rt < 4; ++rt) {
            int nbase = n0 + rt * 16 + quad * 4;
#pragma unroll
            for (int r = 0; r < 4; ++r) {
                int node = nbase + r;
                if (node < N)
                    outp[(size_t)node * HID_C + colg] = f2bf(fmaxf(acc[rt][ci][r] + bv, 0.f));
            }
        }
    }
}

// Layer-2 conv with fused mean-pool partials: h2 never materialized.
template<int KA, int KX>
__global__ __launch_bounds__(256) void conv_mfma_pool_kernel(
    const unsigned short* __restrict__ A, const unsigned short* __restrict__ X,
    const unsigned short* __restrict__ WrP, const unsigned short* __restrict__ WoP,
    const float* __restrict__ bias, const int* __restrict__ batch,
    float* __restrict__ pooled, int N)
{
    __shared__ int sbatch[64];
    const int t = threadIdx.x;
    const int wv = t >> 6;
    const int lane = t & 63;
    const int quad = lane >> 4;
    const int l16 = lane & 15;
    const int n0 = blockIdx.x * 64;

    if (t < 64) {
        int node = n0 + t;
        sbatch[t] = (node < N) ? batch[node] : -1;
    }

    f32x4 acc[4][2];
#pragma unroll
    for (int rt = 0; rt < 4; ++rt)
#pragma unroll
        for (int ci = 0; ci < 2; ++ci)
            acc[rt][ci] = (f32x4){0.f, 0.f, 0.f, 0.f};

    int rowIdx[4];
#pragma unroll
    for (int rt = 0; rt < 4; ++rt) {
        int r = n0 + rt * 16 + l16;
        rowIdx[rt] = (r < N) ? r : (N - 1);
    }

    conv_phase<KA>(A, WrP, rowIdx, quad, lane, wv, acc);
    conv_phase<KX>(X, WoP, rowIdx, quad, lane, wv, acc);
    __syncthreads();

    // bias + relu in place
#pragma unroll
    for (int ci = 0; ci < 2; ++ci) {
        float bv = bias[wv * 32 + ci * 16 + l16];
#pragma unroll
        for (int rt = 0; rt < 4; ++rt)
#pragma unroll
            for (int r = 0; r < 4; ++r)
                acc[rt][ci][r] = fmaxf(acc[rt][ci][r] + bv, 0.f);
    }

    int gmin = sbatch[0];
    int gmax = batch[min(n0 + 63, N - 1)];
    for (int gg = gmin; gg <= gmax; ++gg) {
#pragma unroll
        for (int ci = 0; ci < 2; ++ci) {
            float p = 0.f;
#pragma unroll
            for (int rt = 0; rt < 4; ++rt) {
                int lbase = rt * 16 + quad * 4;
#pragma unroll
                for (int r = 0; r < 4; ++r)
                    if (sbatch[lbase + r] == gg) p += acc[rt][ci][r];
            }
            p += __shfl_xor(p, 16, 64);
            p += __shfl_xor(p, 32, 64);
            if (quad == 0)
                atomicAdd(&pooled[gg * HID_C + wv * 32 + ci * 16 + l16], p);
        }
    }
}

// ---------------------------------------------------------------------------
// Per-graph node counts (batch sorted): run-length per thread, LDS histogram.
// ---------------------------------------------------------------------------
__global__ __launch_bounds__(256) void count_kernel(
    const int* __restrict__ batch, float* __restrict__ cnts, int N)
{
    __shared__ int h[N_GRAPHS_C];
    int t = threadIdx.x;
    if (t < N_GRAPHS_C) h[t] = 0;
    __syncthreads();
    int base = (blockIdx.x * 256 + t) * 16;
    int cur = -1, c = 0;
    for (int i = 0; i < 16; ++i) {
        int n = base + i;
        if (n < N) {
            int g = batch[n];
            if (g != cur) {
                if (cur >= 0) atomicAdd(&h[cur], c);
                cur = g; c = 0;
            }
            ++c;
        }
    }
    if (cur >= 0) atomicAdd(&h[cur], c);
    __syncthreads();
    if (t < N_GRAPHS_C && h[t]) atomicAdd(&cnts[t], (float)h[t]);
}

// ---------------------------------------------------------------------------
// Head: mean, fc1+relu, fc2, softmax (all fp32). One block per graph.
// ---------------------------------------------------------------------------
__global__ __launch_bounds__(128) void head_kernel(
    const float* __restrict__ pooled, const float* __restrict__ cnts,
    const float* __restrict__ fc1w, const float* __restrict__ fc1b,
    const float* __restrict__ fc2w, const float* __restrict__ fc2b,
    float* __restrict__ out)
{
    __shared__ float sp[HID_C];
    __shared__ float so[HID_C];
    __shared__ float sl[64];
    __shared__ float sred[2];
    int g = blockIdx.x;
    int j = threadIdx.x;

    float inv = 1.f / fmaxf(cnts[g], 1.f);
    sp[j] = pooled[g * HID_C + j] * inv;
    __syncthreads();

    float a = fc1b[j];
    for (int k = 0; k < HID_C; ++k) a = fmaf(sp[k], fc1w[k * HID_C + j], a);
    so[j] = fmaxf(a, 0.f);
    __syncthreads();

    if (j < N_ASSETS_C) {
        float l = fc2b[j];
        for (int k = 0; k < HID_C; ++k) l = fmaf(so[k], fc2w[k * N_ASSETS_C + j], l);
        sl[j] = l;
    }
    __syncthreads();

    if (j == 0) {
        float m = -1e30f;
        for (int q = 0; q < N_ASSETS_C; ++q) m = fmaxf(m, sl[q]);
        sred[0] = m;
    }
    __syncthreads();
    if (j < N_ASSETS_C) sl[j] = expf(sl[j] - sred[0]);
    __syncthreads();
    if (j == 0) {
        float s = 0.f;
        for (int q = 0; q < N_ASSETS_C; ++q) s += sl[q];
        sred[1] = 1.f / s;
    }
    __syncthreads();
    if (j < N_ASSETS_C) out[g * N_ASSETS_C + j] = sl[j] * sred[1];
}

// ---------------------------------------------------------------------------
extern "C" void kernel_launch(void* const* d_in, const int* in_sizes, int n_in,
                              void* d_out, int out_size, void* d_ws, size_t ws_size,
                              hipStream_t stream)
{
    const float* x       = (const float*)d_in[0];
    const int*   ei      = (const int*)d_in[1];
    const int*   batch   = (const int*)d_in[2];
    const float* w1_rel  = (const float*)d_in[3];
    const float* b1      = (const float*)d_in[4];
    const float* w1_root = (const float*)d_in[5];
    const float* w2_rel  = (const float*)d_in[6];
    const float* b2      = (const float*)d_in[7];
    const float* w2_root = (const float*)d_in[8];
    const float* fc1w    = (const float*)d_in[9];
    const float* fc1b    = (const float*)d_in[10];
    const float* fc2w    = (const float*)d_in[11];
    const float* fc2b    = (const float*)d_in[12];
    float* out = (float*)d_out;

    char* ws = (char*)d_ws;
    unsigned*       tmp     = (unsigned*)(ws + 0);              //  6,400,000
    int*            col     = (int*)(ws + 6400000);             //  6,400,000
    int*            row_ptr = (int*)(ws + 12800000);            //    400,016
    int*            bbase   = (int*)(ws + 13200016);            //        800
    int*            gcur    = (int*)(ws + 13200816);            //        800
    unsigned short* wp1r    = (unsigned short*)(ws + 13201616); //     32,768
    unsigned short* wp1o    = (unsigned short*)(ws + 13234384); //     32,768
    unsigned short* wp2r    = (unsigned short*)(ws + 13267152); //     65,536
    unsigned short* wp2o    = (unsigned short*)(ws + 13332688); //     65,536
    float*          pooled  = (float*)(ws + 13398224);          //     32,768
    float*          cnts    = (float*)(ws + 13430992);          //        256
    int*            bcnt    = (int*)(ws + 13431248);            //        800
    unsigned short* xb      = (unsigned short*)(ws + 13432048); // 12,800,000
    unsigned short* agg1b   = (unsigned short*)(ws + 26232048); // 12,800,000
    unsigned short* h1b     = (unsigned short*)(ws + 39032048); // 25,600,000
    unsigned char*  h1f     = (unsigned char*)(ws + 64632048);  // 12,800,000
    unsigned short* agg2b   = (unsigned short*)(ws + 77432048); // 25,600,000

    // pooled + cnts + bcnt contiguous: one memset
    hipMemsetAsync(pooled, 0, 33824, stream);

    // ---- casts & weight packing ----
    cast_bf16_kernel<<<(N_NODES_C * IN_DIM_C / 4 + 255) / 256, 256, 0, stream>>>(x, xb, N_NODES_C * IN_DIM_C / 4);
    pack_w_kernel<<<(IN_DIM_C / 32) * 8, 64, 0, stream>>>(w1_rel,  wp1r);
    pack_w_kernel<<<(IN_DIM_C / 32) * 8, 64, 0, stream>>>(w1_root, wp1o);
    pack_w_kernel<<<(HID_C  / 32) * 8, 64, 0, stream>>>(w2_rel,  wp2r);
    pack_w_kernel<<<(HID_C  / 32) * 8, 64, 0, stream>>>(w2_root, wp2o);

    // ---- per-graph counts (independent) ----
    count_kernel<<<(N_NODES_C + 4095) / 4096, 256, 0, stream>>>(batch, cnts, N_NODES_C);

    // ---- CSR build (bucketed counting sort) ----
    bucket_hist_kernel<<<(N_EDGES_C + 2047) / 2048, 256, 0, stream>>>(ei, bcnt);
    bucket_scan_kernel<<<1, 256, 0, stream>>>(bcnt, bbase, gcur);
    partition_kernel<<<NBLK_A, 256, 0, stream>>>(ei, gcur, tmp);
    bucket_sort_kernel<<<NB_BKT, 256, 0, stream>>>(tmp, bbase, row_ptr, col);

    const int ggrid = (N_NODES_C + 3) / 4;       // 25000
    const int cgrid = (N_NODES_C + 63) / 64;     // 1563

    // ---- Layer 1 ----
    gather_bf64_kernel<<<ggrid, 256, 0, stream>>>(xb, row_ptr, col, agg1b);
    conv_mfma_kernel<IN_DIM_C, IN_DIM_C><<<cgrid, 256, 0, stream>>>(
        agg1b, xb, wp1r, wp1o, b1, h1b, N_NODES_C);

    // ---- Layer 2: fp8 copy of h1 for the neighbor-sum only ----
    cast_fp8_kernel<<<(N_NODES_C * HID_C / 8 + 255) / 256, 256, 0, stream>>>(
        h1b, h1f, N_NODES_C * HID_C / 8);
    gather_fp8_kernel<<<ggrid, 256, 0, stream>>>(h1f, row_ptr, col, agg2b);
    conv_mfma_pool_kernel<HID_C, HID_C><<<cgrid, 256, 0, stream>>>(
        agg2b, h1b, wp2r, wp2o, b2, batch, pooled, N_NODES_C);

    // ---- Head ----
    head_kernel<<<N_GRAPHS_C, 128, 0, stream>>>(pooled, cnts, fc1w, fc1b, fc2w, fc2b, out);
}